// Round 3
// baseline (709.821 us; speedup 1.0000x reference)
//
#include <hip/hip_runtime.h>
#include <hip/hip_bf16.h>

#define TT 512
#define BB 4096
#define PF 8   // prefetch depth in the scans

// tanh(x) = 1 - 2/(exp(2x)+1)
__device__ __forceinline__ float fast_tanh(float x){
  float e = __builtin_amdgcn_exp2f(x * 2.885390081777927f);  // 2*log2(e)
  float r = __builtin_amdgcn_rcpf(e + 1.0f);
  return fmaf(-2.0f, r, 1.0f);
}
__device__ __forceinline__ float bflo(unsigned u){ return __uint_as_float(u << 16); }
__device__ __forceinline__ float bfhi(unsigned u){ return __uint_as_float(u & 0xffff0000u); }
__device__ __forceinline__ unsigned short bfbits(float f){
  __hip_bfloat16 b = __float2bfloat16(f);
  return *reinterpret_cast<unsigned short*>(&b);
}

// DPP quad_perm broadcast of slot J within each 4-lane quad.
template<int J>
__device__ __forceinline__ float qpb(float v){
  return __int_as_float(__builtin_amdgcn_mov_dpp(__float_as_int(v), J*0x55, 0xF, 0xF, true));
}
// DPP row_half_mirror: lane l -> lane (7 - l) within each 8-lane half (pure VALU).
__device__ __forceinline__ float hmir(float v){
  return __int_as_float(__builtin_amdgcn_mov_dpp(__float_as_int(v), 0x141, 0xF, 0xF, true));
}

// h_new = tanh(at + Whh_row . h_group); whq: own-quad slots, whs: mirrored
// other-quad slots (whs[j] must hold Whh[i][4*(1-qp) + (3-j)]).
__device__ __forceinline__ float rstep(float h, float at,
                                       const float* whq, const float* whs){
  float hs = hmir(h);
  float r0 = at, r1 = 0.f;
  r0 = fmaf(whq[0], qpb<0>(h),  r0);
  r1 = fmaf(whs[0], qpb<0>(hs), r1);
  r0 = fmaf(whq[1], qpb<1>(h),  r0);
  r1 = fmaf(whs[1], qpb<1>(hs), r1);
  r0 = fmaf(whq[2], qpb<2>(h),  r0);
  r1 = fmaf(whs[2], qpb<2>(hs), r1);
  r0 = fmaf(whq[3], qpb<3>(h),  r0);
  r1 = fmaf(whs[3], qpb<3>(hs), r1);
  return fast_tanh(r0 + r1);
}

// Layer 0: x [B][6][T] f32 -> plane [T][B][16] bf16 (f = dir*8 + i).
// 8 lanes per (b,dir); proj (6 inputs) fused in-scan, f32 precision.
__global__ __launch_bounds__(256) void rnn_l0(
    const float* __restrict__ x,
    const float* __restrict__ Wih, const float* __restrict__ Whh,
    const float* __restrict__ bih, const float* __restrict__ bhh,
    __hip_bfloat16* __restrict__ outp)
{
  const int tid  = blockIdx.x*256 + threadIdx.x;
  const int lane = tid & 63;
  const int wave = tid >> 6;
  const int g = lane >> 3, i = lane & 7;
  const int dir = g >> 2;
  const int b   = wave*4 + (g & 3);
  const int qp  = (lane >> 2) & 1;

  float wi[6], whq[4], whs[4];
  #pragma unroll
  for (int c=0;c<6;c++) wi[c] = Wih[(dir*8+i)*6 + c];
  #pragma unroll
  for (int j=0;j<4;j++){
    whq[j] = Whh[(dir*8+i)*8 + qp*4 + j];
    whs[j] = Whh[(dir*8+i)*8 + (1-qp)*4 + (3-j)];
  }
  const float bias = bih[dir*8+i] + bhh[dir*8+i];

  const float* xb = x + (size_t)b*6*TT;
  __hip_bfloat16* op = outp + b*16 + dir*8 + i;

  float bufX[PF][6];
  #pragma unroll
  for (int k=0;k<PF;k++){
    const int tq = dir ? (TT-1-k) : k;
    #pragma unroll
    for (int c=0;c<6;c++) bufX[k][c] = xb[c*TT + tq];
  }

  float h = 0.f;
  #pragma unroll 1
  for (int s=0; s<TT; s+=PF){
    #pragma unroll
    for (int k=0;k<PF;k++){
      const int step = s+k;
      const int t = dir ? (TT-1-step) : step;
      float xc[6];
      #pragma unroll
      for (int c=0;c<6;c++) xc[c] = bufX[k][c];
      const int ns = step + PF;
      if (ns < TT){
        const int tn = dir ? (TT-1-ns) : ns;
        #pragma unroll
        for (int c=0;c<6;c++) bufX[k][c] = xb[c*TT + tn];
      }
      float a0=bias, a1=0.f;
      a0=fmaf(wi[0],xc[0],a0); a1=fmaf(wi[1],xc[1],a1);
      a0=fmaf(wi[2],xc[2],a0); a1=fmaf(wi[3],xc[3],a1);
      a0=fmaf(wi[4],xc[4],a0); a1=fmaf(wi[5],xc[5],a1);
      h = rstep(h, a0+a1, whq, whs);
      op[(size_t)t*(BB*16)] = __float2bfloat16(h);
    }
  }
}

// Projection for layers 1..3: inp [T][B][16] bf16 -> xout [T][B][NOUT] bf16,
// xout[t][b][f] = bias[f] + sum_c W[f][c]*in[c]. Elementwise in (t,b): safe
// to run IN-PLACE (inp == xout). One thread per (t,b); fully occupied.
template<int NOUT>
__global__ __launch_bounds__(256) void projN(
    const __hip_bfloat16* __restrict__ inp,
    const float* __restrict__ Wih,          // rows f = dir*8+i, 16 cols
    const float* __restrict__ bih, const float* __restrict__ bhh,
    __hip_bfloat16* __restrict__ xout)
{
  const int tid = blockIdx.x*256 + threadIdx.x;   // t*B + b
  const uint4* ip = (const uint4*)inp + (size_t)tid*2;
  uint4 va = ip[0], vb = ip[1];
  float in[16];
  in[0]=bflo(va.x);  in[1]=bfhi(va.x);  in[2]=bflo(va.y);  in[3]=bfhi(va.y);
  in[4]=bflo(va.z);  in[5]=bfhi(va.z);  in[6]=bflo(va.w);  in[7]=bfhi(va.w);
  in[8]=bflo(vb.x);  in[9]=bfhi(vb.x);  in[10]=bflo(vb.y); in[11]=bfhi(vb.y);
  in[12]=bflo(vb.z); in[13]=bfhi(vb.z); in[14]=bflo(vb.w); in[15]=bfhi(vb.w);

  unsigned out[NOUT/2];
  #pragma unroll
  for (int fp=0; fp<NOUT/2; ++fp){
    float acc[2];
    #pragma unroll
    for (int u=0;u<2;u++){
      const int f = fp*2+u;
      float a = bih[f] + bhh[f];
      #pragma unroll
      for (int c=0;c<16;c++) a = fmaf(Wih[f*16+c], in[c], a);
      acc[u] = a;
    }
    out[fp] = (unsigned)bfbits(acc[0]) | ((unsigned)bfbits(acc[1]) << 16);
  }
  if (NOUT == 16){
    uint4* opq = (uint4*)xout + (size_t)tid*2;
    opq[0] = make_uint4(out[0], out[1], out[2], out[3]);
    opq[1] = make_uint4(out[4], out[5], out[6], out[7]);
  } else {
    uint4* opq = (uint4*)xout + (size_t)tid;
    opq[0] = make_uint4(out[0], out[1], out[2], out[3]);
  }
}

// Recurrence-only scan. xin [T][B][NIN] bf16 preactivations (bias included).
// LAST=0: NIN=16, writes plane [T][B][16]. LAST=1: NIN=8 (fwd only),
// writes final fwd h to lastv[b*16+i].
template<int LAST>
__global__ __launch_bounds__(256) void scanN(
    const __hip_bfloat16* __restrict__ xin,
    const float* __restrict__ Whh,
    __hip_bfloat16* __restrict__ outp, float* __restrict__ lastv)
{
  const int tid  = blockIdx.x*256 + threadIdx.x;
  const int lane = tid & 63;
  const int wave = tid >> 6;
  const int g = lane >> 3, i = lane & 7;
  const int dir = LAST ? 0 : (g >> 2);
  const int b   = LAST ? (wave*8 + g) : (wave*4 + (g & 3));
  const int qp  = (lane >> 2) & 1;
  const int NIN = LAST ? 8 : 16;

  float whq[4], whs[4];
  #pragma unroll
  for (int j=0;j<4;j++){
    whq[j] = Whh[(dir*8+i)*8 + qp*4 + j];
    whs[j] = Whh[(dir*8+i)*8 + (1-qp)*4 + (3-j)];
  }

  const unsigned short* xp = (const unsigned short*)xin
                           + (LAST ? (b*8 + i) : (b*16 + dir*8 + i));
  __hip_bfloat16* op = LAST ? nullptr : (outp + b*16 + dir*8 + i);

  unsigned short bufX[PF];
  #pragma unroll
  for (int k=0;k<PF;k++){
    const int tq = dir ? (TT-1-k) : k;
    bufX[k] = xp[(size_t)tq*(BB*NIN)];
  }

  float h = 0.f;
  #pragma unroll 1
  for (int s=0; s<TT; s+=PF){
    #pragma unroll
    for (int k=0;k<PF;k++){
      const int step = s+k;
      const int t = dir ? (TT-1-step) : step;
      const float at = __uint_as_float(((unsigned)bufX[k]) << 16);
      const int ns = step + PF;
      if (ns < TT){
        const int tn = dir ? (TT-1-ns) : ns;
        bufX[k] = xp[(size_t)tn*(BB*NIN)];
      }
      h = rstep(h, at, whq, whs);
      if (!LAST) op[(size_t)t*(BB*16)] = __float2bfloat16(h);
    }
  }
  if (LAST) lastv[b*16 + i] = h;
}

// FC + layer-3 bwd at t=T-1 (= tanh(proj(in[T-1])) since h0=0).
__global__ __launch_bounds__(256) void fc_k(
    const __hip_bfloat16* __restrict__ plane2,  // layer-2 output [T][B][16]
    const float* __restrict__ Wih3, const float* __restrict__ bih3, const float* __restrict__ bhh3,
    const float* __restrict__ lastv,
    const float* __restrict__ fcw, const float* __restrict__ fcb,
    float* __restrict__ outp)
{
  const int b = blockIdx.x*256 + threadIdx.x;
  const uint4* pp = (const uint4*)(plane2 + (size_t)(TT-1)*BB*16) + (size_t)b*2;
  uint4 va = pp[0], vb = pp[1];
  float inv[16];
  inv[0]=bflo(va.x);  inv[1]=bfhi(va.x);  inv[2]=bflo(va.y);  inv[3]=bfhi(va.y);
  inv[4]=bflo(va.z);  inv[5]=bfhi(va.z);  inv[6]=bflo(va.w);  inv[7]=bfhi(va.w);
  inv[8]=bflo(vb.x);  inv[9]=bfhi(vb.x);  inv[10]=bflo(vb.y); inv[11]=bfhi(vb.y);
  inv[12]=bflo(vb.z); inv[13]=bfhi(vb.z); inv[14]=bflo(vb.w); inv[15]=bfhi(vb.w);
  float lv[16];
  #pragma unroll
  for (int k=0;k<8;k++) lv[k] = lastv[b*16+k];
  #pragma unroll
  for (int ii=0; ii<8; ++ii){
    float a = bih3[8+ii] + bhh3[8+ii];     // dir=1 rows
    #pragma unroll
    for (int j=0;j<16;j++) a = fmaf(Wih3[(8+ii)*16 + j], inv[j], a);
    lv[8+ii] = fast_tanh(a);
  }
  #pragma unroll
  for (int c=0;c<2;c++){
    float o = fcb[c];
    #pragma unroll
    for (int k=0;k<16;k++) o = fmaf(fcw[c*16+k], lv[k], o);
    outp[b*2+c] = o;
  }
}

extern "C" void kernel_launch(void* const* d_in, const int* in_sizes, int n_in,
                              void* d_out, int out_size, void* d_ws, size_t ws_size,
                              hipStream_t stream)
{
  const float* x    = (const float*)d_in[0];
  const float* Wih0 = (const float*)d_in[1];
  const float* Whh0 = (const float*)d_in[2];
  const float* bih0 = (const float*)d_in[3];
  const float* bhh0 = (const float*)d_in[4];
  const float* Wih  = (const float*)d_in[5];   // [3][2][8][16]
  const float* Whh  = (const float*)d_in[6];   // [3][2][8][8]
  const float* bih  = (const float*)d_in[7];   // [3][2][8]
  const float* bhh  = (const float*)d_in[8];
  const float* fcw  = (const float*)d_in[9];
  const float* fcb  = (const float*)d_in[10];

  const size_t PLANE = (size_t)TT*BB*16;       // 32M bf16 = 64 MB
  __hip_bfloat16* A = (__hip_bfloat16*)d_ws;
  __hip_bfloat16* B = A + PLANE;
  float* lastv = (float*)(B + PLANE);          // [B][16] f32
  if (ws_size < PLANE*2*sizeof(__hip_bfloat16) + (size_t)BB*16*sizeof(float)) return;

  // L0 (proj fused): x -> A (planes L0)
  rnn_l0<<<256,256,0,stream>>>(x, Wih0, Whh0, bih0, bhh0, A);
  // P1 in-place: A(planes L0) -> A(xin1);  S1: A -> B(planes L1)
  projN<16><<<8192,256,0,stream>>>(A, Wih,     bih,    bhh,    A);
  scanN<0><<<256,256,0,stream>>>(A, Whh,     B, nullptr);
  // P2 in-place: B -> B(xin2);  S2: B -> A(planes L2, kept for FC)
  projN<16><<<8192,256,0,stream>>>(B, Wih+256, bih+16, bhh+16, B);
  scanN<0><<<256,256,0,stream>>>(B, Whh+128, A, nullptr);
  // P3 (fwd rows only): A(planes L2) -> B as [T][B][8];  S3: B -> lastv
  projN<8><<<8192,256,0,stream>>>(A, Wih+512, bih+32, bhh+32, B);
  scanN<1><<<128,256,0,stream>>>(B, Whh+256, nullptr, lastv);
  // layer-3 bwd single step + FC
  fc_k<<<16,256,0,stream>>>(A, Wih+512, bih+32, bhh+32, lastv, fcw, fcb, (float*)d_out);
}

// Round 4
// 262.477 us; speedup vs baseline: 2.7043x; 2.7043x over previous
//
#include <hip/hip_runtime.h>
#include <hip/hip_bf16.h>

#define TT 512
#define BB 4096

// tanh(x) = 1 - 2/(exp(2x)+1)
__device__ __forceinline__ float fast_tanh(float x){
  float e = __builtin_amdgcn_exp2f(x * 2.885390081777927f);  // 2*log2(e)
  float r = __builtin_amdgcn_rcpf(e + 1.0f);
  return fmaf(-2.0f, r, 1.0f);
}
__device__ __forceinline__ float bflo(unsigned u){ return __uint_as_float(u << 16); }
__device__ __forceinline__ float bfhi(unsigned u){ return __uint_as_float(u & 0xffff0000u); }
__device__ __forceinline__ unsigned short bfbits(float f){
  __hip_bfloat16 b = __float2bfloat16(f);
  return *reinterpret_cast<unsigned short*>(&b);
}
// DPP quad_perm broadcast of slot J within each 4-lane quad.
template<int J>
__device__ __forceinline__ float qpb(float v){
  return __int_as_float(__builtin_amdgcn_mov_dpp(__float_as_int(v), J*0x55, 0xF, 0xF, true));
}
// DPP row_half_mirror: lane l -> (7-l) within each 8-lane half.
__device__ __forceinline__ float hmir(float v){
  return __int_as_float(__builtin_amdgcn_mov_dpp(__float_as_int(v), 0x141, 0xF, 0xF, true));
}
__device__ __forceinline__ unsigned ror16(unsigned u){
  return __builtin_amdgcn_alignbit(u, u, 16);
}
// Reverse the 8 bf16 elements of a uint4 (dword reverse + halfword swap).
__device__ __forceinline__ uint4 rev8(uint4 v){
  return make_uint4(ror16(v.w), ror16(v.z), ror16(v.y), ror16(v.x));
}

// h_new = tanh(at + Whh_row . h_group); whq own-quad, whs mirrored other-quad
// (whs[j] = Whh[i][4*(1-qp) + (3-j)]).
__device__ __forceinline__ float rstep(float h, float at,
                                       const float* whq, const float* whs){
  float hs = hmir(h);
  float r0 = at, r1 = 0.f;
  r0 = fmaf(whq[0], qpb<0>(h),  r0);
  r1 = fmaf(whs[0], qpb<0>(hs), r1);
  r0 = fmaf(whq[1], qpb<1>(h),  r0);
  r1 = fmaf(whs[1], qpb<1>(hs), r1);
  r0 = fmaf(whq[2], qpb<2>(h),  r0);
  r1 = fmaf(whs[2], qpb<2>(hs), r1);
  r0 = fmaf(whq[3], qpb<3>(h),  r0);
  r1 = fmaf(whs[3], qpb<3>(hs), r1);
  return fast_tanh(r0 + r1);
}

// ---------------- proj0: x [B][6][T] f32 -> X0 streams [2][B][8][T] bf16 ----
// wave = (b, half); lane covers a 4-timestep chunk. Bias folded in.
__global__ __launch_bounds__(256) void proj0(
    const float* __restrict__ x,
    const float* __restrict__ Wih, const float* __restrict__ bih,
    const float* __restrict__ bhh,
    __hip_bfloat16* __restrict__ xout)
{
  const int tid  = threadIdx.x;
  const int wid  = blockIdx.x*4 + (tid>>6);
  const int b    = wid >> 1;
  const int half = wid & 1;
  const int lane = tid & 63;
  const int t0   = (half*64 + lane)*4;

  float in_[6][4];
  #pragma unroll
  for (int c=0;c<6;++c){
    const float4 v = *(const float4*)(x + ((size_t)b*6 + c)*TT + t0);
    in_[c][0]=v.x; in_[c][1]=v.y; in_[c][2]=v.z; in_[c][3]=v.w;
  }
  #pragma unroll
  for (int f=0; f<16; ++f){
    const float a0 = bih[f] + bhh[f];
    float acc[4] = {a0,a0,a0,a0};
    #pragma unroll
    for (int c=0;c<6;++c){
      const float w = Wih[f*6+c];
      acc[0]=fmaf(w,in_[c][0],acc[0]); acc[1]=fmaf(w,in_[c][1],acc[1]);
      acc[2]=fmaf(w,in_[c][2],acc[2]); acc[3]=fmaf(w,in_[c][3],acc[3]);
    }
    uint2 o;
    o.x = (unsigned)bfbits(acc[0]) | ((unsigned)bfbits(acc[1])<<16);
    o.y = (unsigned)bfbits(acc[2]) | ((unsigned)bfbits(acc[3])<<16);
    *(uint2*)((char*)xout + (((((size_t)(f>>3))*BB + b)*8 + (f&7))*TT + t0)*2) = o;
  }
}

// ---------------- projN: plane [2][B][8][T] -> xin [NOUT/8-dirs][B][8][T] ---
template<int NOUT>
__global__ __launch_bounds__(256) void projN(
    const __hip_bfloat16* __restrict__ inp,
    const float* __restrict__ Wih,          // rows f = dir*8+i, 16 cols
    const float* __restrict__ bih, const float* __restrict__ bhh,
    __hip_bfloat16* __restrict__ xout)
{
  const int tid  = threadIdx.x;
  const int wid  = blockIdx.x*4 + (tid>>6);
  const int b    = wid >> 1;
  const int half = wid & 1;
  const int lane = tid & 63;
  const int t0   = (half*64 + lane)*4;

  float in_[16][4];
  #pragma unroll
  for (int d=0; d<2; ++d)
    #pragma unroll
    for (int c=0;c<8;++c){
      const uint2 v = *(const uint2*)((const char*)inp +
          (((((size_t)d)*BB + b)*8 + c)*TT + t0)*2);
      const int f = d*8+c;
      in_[f][0]=bflo(v.x); in_[f][1]=bfhi(v.x);
      in_[f][2]=bflo(v.y); in_[f][3]=bfhi(v.y);
    }
  #pragma unroll
  for (int f=0; f<NOUT; ++f){
    const float a0 = bih[f] + bhh[f];
    float acc[4] = {a0,a0,a0,a0};
    #pragma unroll
    for (int c=0;c<16;++c){
      const float w = Wih[f*16+c];
      acc[0]=fmaf(w,in_[c][0],acc[0]); acc[1]=fmaf(w,in_[c][1],acc[1]);
      acc[2]=fmaf(w,in_[c][2],acc[2]); acc[3]=fmaf(w,in_[c][3],acc[3]);
    }
    uint2 o;
    o.x = (unsigned)bfbits(acc[0]) | ((unsigned)bfbits(acc[1])<<16);
    o.y = (unsigned)bfbits(acc[2]) | ((unsigned)bfbits(acc[3])<<16);
    *(uint2*)((char*)xout + (((((size_t)(f>>3))*BB + b)*8 + (f&7))*TT + t0)*2) = o;
  }
}

// ---------------- scan: pure recurrence over stream-major xin ---------------
// LAST=0: dir = wave&1, both dirs, writes plane + tail[b*16+dir*8+i].
// LAST=1: fwd only, writes tail[b*16+i] only.
template<int LAST>
__global__ __launch_bounds__(256) void scanK(
    const __hip_bfloat16* __restrict__ xin,
    const float* __restrict__ Whh,
    __hip_bfloat16* __restrict__ plane,
    float* __restrict__ tail)
{
  const int tid  = threadIdx.x;
  const int wid  = blockIdx.x*4 + (tid>>6);
  const int lane = tid & 63;
  const int g = lane>>3, i = lane&7, qp = (lane>>2)&1;
  const int dirw = LAST ? 0 : (wid & 1);
  const int b    = LAST ? (wid*8 + g) : ((wid>>1)*8 + g);

  float whq[4], whs[4];
  #pragma unroll
  for (int j=0;j<4;j++){
    whq[j] = Whh[(dirw*8+i)*8 + qp*4 + j];
    whs[j] = Whh[(dirw*8+i)*8 + (1-qp)*4 + (3-j)];
  }

  const size_t sbyte = (((((size_t)dirw)*BB + b)*8 + i)*TT)*2;
  const char* xb = (const char*)xin + sbyte;
  char*       ob = (char*)plane + sbyte;

  auto ldw = [&](int w)->uint4{
    const int t0 = dirw ? (TT-8-8*w) : 8*w;
    return *(const uint4*)(xb + t0*2);
  };

  uint4 b0 = ldw(0), b1 = ldw(1), b2 = ldw(2), b3;
  float h = 0.f, hT0 = 0.f;

  auto window = [&](uint4& cur, uint4& nxt, int w){
    int wl = w+3; if (wl > 63) wl = 63;
    nxt = ldw(wl);                            // 3-window lookahead
    uint4 v = cur;
    if (dirw) v = rev8(v);                    // uniform per-wave branch
    unsigned od0=0, od1=0, od2=0, od3=0;
    #pragma unroll
    for (int k=0;k<8;++k){
      const unsigned dwv = ((k>>1)==0)?v.x:((k>>1)==1)?v.y:((k>>1)==2)?v.z:v.w;
      const float at = (k&1) ? bfhi(dwv) : bflo(dwv);
      h = rstep(h, at, whq, whs);
      if (k==0 && w==0) hT0 = h;
      if (!LAST){
        const unsigned hb = bfbits(h);
        if ((k&1)==0){
          if ((k>>1)==0) od0=hb; else if ((k>>1)==1) od1=hb;
          else if ((k>>1)==2) od2=hb; else od3=hb;
        } else {
          if ((k>>1)==0) od0|=hb<<16; else if ((k>>1)==1) od1|=hb<<16;
          else if ((k>>1)==2) od2|=hb<<16; else od3|=hb<<16;
        }
      }
    }
    if (!LAST){
      uint4 o = make_uint4(od0,od1,od2,od3);
      if (dirw) o = rev8(o);
      const int t0 = dirw ? (TT-8-8*w) : 8*w;
      *(uint4*)(ob + t0*2) = o;
    }
  };

  #pragma unroll 1
  for (int q=0;q<16;++q){
    window(b0,b3,4*q+0);
    window(b1,b0,4*q+1);
    window(b2,b1,4*q+2);
    window(b3,b2,4*q+3);
  }
  tail[b*16 + dirw*8 + i] = dirw ? hT0 : h;
}

// ---------------- fc: layer3-bwd@T-1 (= tanh(proj(tail2))) + FC -------------
__global__ __launch_bounds__(256) void fc_k(
    const float* __restrict__ tail2, const float* __restrict__ tail3,
    const float* __restrict__ Wih3, const float* __restrict__ bih3,
    const float* __restrict__ bhh3,
    const float* __restrict__ fcw, const float* __restrict__ fcb,
    float* __restrict__ outp)
{
  const int b = blockIdx.x*256 + threadIdx.x;
  float inv[16];
  #pragma unroll
  for (int c=0;c<16;c++) inv[c] = tail2[b*16+c];
  float lv[16];
  #pragma unroll
  for (int k=0;k<8;k++) lv[k] = tail3[b*16+k];
  #pragma unroll
  for (int ii=0; ii<8; ++ii){
    float a = bih3[8+ii] + bhh3[8+ii];       // dir=1 rows
    #pragma unroll
    for (int j=0;j<16;j++) a = fmaf(Wih3[(8+ii)*16 + j], inv[j], a);
    lv[8+ii] = fast_tanh(a);
  }
  #pragma unroll
  for (int c=0;c<2;c++){
    float o = fcb[c];
    #pragma unroll
    for (int k=0;k<16;k++) o = fmaf(fcw[c*16+k], lv[k], o);
    outp[b*2+c] = o;
  }
}

extern "C" void kernel_launch(void* const* d_in, const int* in_sizes, int n_in,
                              void* d_out, int out_size, void* d_ws, size_t ws_size,
                              hipStream_t stream)
{
  const float* x    = (const float*)d_in[0];
  const float* Wih0 = (const float*)d_in[1];
  const float* Whh0 = (const float*)d_in[2];
  const float* bih0 = (const float*)d_in[3];
  const float* bhh0 = (const float*)d_in[4];
  const float* Wih  = (const float*)d_in[5];   // [3][2][8][16]
  const float* WhhL = (const float*)d_in[6];   // [3][2][8][8]
  const float* bih  = (const float*)d_in[7];   // [3][2][8]
  const float* bhh  = (const float*)d_in[8];
  const float* fcw  = (const float*)d_in[9];
  const float* fcb  = (const float*)d_in[10];

  const size_t PLANE_E = (size_t)2*BB*8*TT;    // 33.5M elems = 64 MB bf16
  __hip_bfloat16* A  = (__hip_bfloat16*)d_ws;
  __hip_bfloat16* Bb = A + PLANE_E;
  float* tail2 = (float*)(Bb + PLANE_E);       // [B][16] f32
  float* tail3 = tail2 + (size_t)BB*16;
  if (ws_size < PLANE_E*2*sizeof(__hip_bfloat16) + (size_t)BB*16*4*2) return;

  // layer 0
  proj0<<<2048,256,0,stream>>>(x, Wih0, bih0, bhh0, A);
  scanK<0><<<256,256,0,stream>>>(A, Whh0, Bb, tail2);
  // layer 1
  projN<16><<<2048,256,0,stream>>>(Bb, Wih,     bih,    bhh,    A);
  scanK<0><<<256,256,0,stream>>>(A, WhhL,      Bb, tail2);
  // layer 2
  projN<16><<<2048,256,0,stream>>>(Bb, Wih+256, bih+16, bhh+16, A);
  scanK<0><<<256,256,0,stream>>>(A, WhhL+128,  Bb, tail2);
  // layer 3 (fwd only)
  projN<8><<<2048,256,0,stream>>>(Bb, Wih+512, bih+32, bhh+32, A);
  scanK<1><<<128,256,0,stream>>>(A, WhhL+256,  Bb /*unused*/, tail3);
  // layer-3 bwd single step + FC
  fc_k<<<16,256,0,stream>>>(tail2, tail3, Wih+512, bih+32, bhh+32,
                            fcw, fcb, (float*)d_out);
}

// Round 5
// 242.065 us; speedup vs baseline: 2.9324x; 1.0843x over previous
//
#include <hip/hip_runtime.h>
#include <hip/hip_bf16.h>

#define TT 512
#define BB 4096

// tanh(x) = 1 - 2/(exp(2x)+1)
__device__ __forceinline__ float fast_tanh(float x){
  float e = __builtin_amdgcn_exp2f(x * 2.885390081777927f);  // 2*log2(e)
  float r = __builtin_amdgcn_rcpf(e + 1.0f);
  return fmaf(-2.0f, r, 1.0f);
}
__device__ __forceinline__ float bflo(unsigned u){ return __uint_as_float(u << 16); }
__device__ __forceinline__ float bfhi(unsigned u){ return __uint_as_float(u & 0xffff0000u); }
__device__ __forceinline__ unsigned short bfbits(float f){
  __hip_bfloat16 b = __float2bfloat16(f);
  return *reinterpret_cast<unsigned short*>(&b);
}
// DPP quad_perm broadcast of slot J within each 4-lane quad.
template<int J>
__device__ __forceinline__ float qpb(float v){
  return __int_as_float(__builtin_amdgcn_mov_dpp(__float_as_int(v), J*0x55, 0xF, 0xF, true));
}
// DPP row_half_mirror: lane l -> (7-l) within each 8-lane half.
__device__ __forceinline__ float hmir(float v){
  return __int_as_float(__builtin_amdgcn_mov_dpp(__float_as_int(v), 0x141, 0xF, 0xF, true));
}
__device__ __forceinline__ unsigned ror16(unsigned u){
  return __builtin_amdgcn_alignbit(u, u, 16);
}
// Reverse the 8 bf16 elements of a uint4.
__device__ __forceinline__ uint4 rev8(uint4 v){
  return make_uint4(ror16(v.w), ror16(v.z), ror16(v.y), ror16(v.x));
}

// h_new = tanh(at + Whh_row . h_group); whq own-quad, whs mirrored other-quad
// (whs[j] = Whh[i][4*(1-qp) + (3-j)]).
__device__ __forceinline__ float rstep(float h, float at,
                                       const float* whq, const float* whs){
  float hs = hmir(h);
  float r0 = at, r1 = 0.f;
  r0 = fmaf(whq[0], qpb<0>(h),  r0);
  r1 = fmaf(whs[0], qpb<0>(hs), r1);
  r0 = fmaf(whq[1], qpb<1>(h),  r0);
  r1 = fmaf(whs[1], qpb<1>(hs), r1);
  r0 = fmaf(whq[2], qpb<2>(h),  r0);
  r1 = fmaf(whs[2], qpb<2>(hs), r1);
  r0 = fmaf(whq[3], qpb<3>(h),  r0);
  r1 = fmaf(whs[3], qpb<3>(hs), r1);
  return fast_tanh(r0 + r1);
}

// ---------------- proj0: x [B][6][T] f32 -> X0 streams [2][B][8][T] bf16 ----
__global__ __launch_bounds__(256) void proj0(
    const float* __restrict__ x,
    const float* __restrict__ Wih, const float* __restrict__ bih,
    const float* __restrict__ bhh,
    __hip_bfloat16* __restrict__ xout)
{
  const int tid  = threadIdx.x;
  const int wid  = blockIdx.x*4 + (tid>>6);
  const int b    = wid >> 1;
  const int half = wid & 1;
  const int lane = tid & 63;
  const int t0   = (half*64 + lane)*4;

  float in_[6][4];
  #pragma unroll
  for (int c=0;c<6;++c){
    const float4 v = *(const float4*)(x + ((size_t)b*6 + c)*TT + t0);
    in_[c][0]=v.x; in_[c][1]=v.y; in_[c][2]=v.z; in_[c][3]=v.w;
  }
  #pragma unroll
  for (int f=0; f<16; ++f){
    const float a0 = bih[f] + bhh[f];
    float acc[4] = {a0,a0,a0,a0};
    #pragma unroll
    for (int c=0;c<6;++c){
      const float w = Wih[f*6+c];
      acc[0]=fmaf(w,in_[c][0],acc[0]); acc[1]=fmaf(w,in_[c][1],acc[1]);
      acc[2]=fmaf(w,in_[c][2],acc[2]); acc[3]=fmaf(w,in_[c][3],acc[3]);
    }
    uint2 o;
    o.x = (unsigned)bfbits(acc[0]) | ((unsigned)bfbits(acc[1])<<16);
    o.y = (unsigned)bfbits(acc[2]) | ((unsigned)bfbits(acc[3])<<16);
    *(uint2*)((char*)xout + (((((size_t)(f>>3))*BB + b)*8 + (f&7))*TT + t0)*2) = o;
  }
}

// ---------------- projN: plane [2][B][8][T] -> xin [.][B][8][T] -------------
template<int NOUT>
__global__ __launch_bounds__(256) void projN(
    const __hip_bfloat16* __restrict__ inp,
    const float* __restrict__ Wih,          // rows f = dir*8+i, 16 cols
    const float* __restrict__ bih, const float* __restrict__ bhh,
    __hip_bfloat16* __restrict__ xout)
{
  const int tid  = threadIdx.x;
  const int wid  = blockIdx.x*4 + (tid>>6);
  const int b    = wid >> 1;
  const int half = wid & 1;
  const int lane = tid & 63;
  const int t0   = (half*64 + lane)*4;

  float in_[16][4];
  #pragma unroll
  for (int d=0; d<2; ++d)
    #pragma unroll
    for (int c=0;c<8;++c){
      const uint2 v = *(const uint2*)((const char*)inp +
          (((((size_t)d)*BB + b)*8 + c)*TT + t0)*2);
      const int f = d*8+c;
      in_[f][0]=bflo(v.x); in_[f][1]=bfhi(v.x);
      in_[f][2]=bflo(v.y); in_[f][3]=bfhi(v.y);
    }
  #pragma unroll
  for (int f=0; f<NOUT; ++f){
    const float a0 = bih[f] + bhh[f];
    float acc[4] = {a0,a0,a0,a0};
    #pragma unroll
    for (int c=0;c<16;++c){
      const float w = Wih[f*16+c];
      acc[0]=fmaf(w,in_[c][0],acc[0]); acc[1]=fmaf(w,in_[c][1],acc[1]);
      acc[2]=fmaf(w,in_[c][2],acc[2]); acc[3]=fmaf(w,in_[c][3],acc[3]);
    }
    uint2 o;
    o.x = (unsigned)bfbits(acc[0]) | ((unsigned)bfbits(acc[1])<<16);
    o.y = (unsigned)bfbits(acc[2]) | ((unsigned)bfbits(acc[3])<<16);
    *(uint2*)((char*)xout + (((((size_t)(f>>3))*BB + b)*8 + (f&7))*TT + t0)*2) = o;
  }
}

// ---------------- scan: pure recurrence over stream-major xin ---------------
// Group = 4 windows = 32 steps = 64 bytes per lane. Loads double-buffered one
// group ahead; stores batched per group into one fully-dirty 64B block.
template<int LAST>
__global__ __launch_bounds__(256) void scanK(
    const __hip_bfloat16* __restrict__ xin,
    const float* __restrict__ Whh,
    __hip_bfloat16* __restrict__ plane,
    float* __restrict__ tail)
{
  const int tid  = threadIdx.x;
  const int wid  = blockIdx.x*4 + (tid>>6);
  const int lane = tid & 63;
  const int g = lane>>3, i = lane&7, qp = (lane>>2)&1;
  const int dirw = LAST ? 0 : (wid & 1);
  const int b    = LAST ? (wid*8 + g) : ((wid>>1)*8 + g);

  float whq[4], whs[4];
  #pragma unroll
  for (int j=0;j<4;j++){
    whq[j] = Whh[(dirw*8+i)*8 + qp*4 + j];
    whs[j] = Whh[(dirw*8+i)*8 + (1-qp)*4 + (3-j)];
  }

  const size_t sbyte = (((((size_t)dirw)*BB + b)*8 + i)*TT)*2;
  const char* xb = (const char*)xin + sbyte;
  char*       ob = (char*)plane + sbyte;

  // window w (global 0..63): t0 = dirw ? TT-8-8w : 8w
  auto ldgrp = [&](uint4* dst, int grp){
    #pragma unroll
    for (int w=0;w<4;++w){
      const int gw = 4*grp + w;
      const int t0 = dirw ? (TT-8-8*gw) : 8*gw;
      dst[w] = *(const uint4*)(xb + t0*2);
    }
  };

  uint4 bufA[4], bufB[4];
  ldgrp(bufA, 0);
  ldgrp(bufB, 1);

  // bwd tail (h at t=TT-1) = tanh(first preactivation) since h0 = 0.
  float tail_bwd = 0.f;
  if (dirw) tail_bwd = fast_tanh(bfhi(bufA[0].w));

  float h = 0.f;

  auto doGroup = [&](uint4* cur, int grp){
    uint4 od[4];
    #pragma unroll
    for (int w=0;w<4;++w){
      uint4 v = cur[w];
      if (dirw) v = rev8(v);
      unsigned o0=0,o1=0,o2=0,o3=0;
      #pragma unroll
      for (int k=0;k<8;++k){
        const unsigned dwv = ((k>>1)==0)?v.x:((k>>1)==1)?v.y:((k>>1)==2)?v.z:v.w;
        const float at = (k&1) ? bfhi(dwv) : bflo(dwv);
        h = rstep(h, at, whq, whs);
        if (!LAST){
          const unsigned hb = bfbits(h);
          if ((k&1)==0){
            if ((k>>1)==0) o0=hb; else if ((k>>1)==1) o1=hb;
            else if ((k>>1)==2) o2=hb; else o3=hb;
          } else {
            if ((k>>1)==0) o0|=hb<<16; else if ((k>>1)==1) o1|=hb<<16;
            else if ((k>>1)==2) o2|=hb<<16; else o3|=hb<<16;
          }
        }
      }
      if (!LAST){
        uint4 o = make_uint4(o0,o1,o2,o3);
        od[w] = dirw ? rev8(o) : o;
      }
    }
    if (!LAST){
      #pragma unroll
      for (int w=0;w<4;++w){
        const int gw = 4*grp + w;
        const int t0 = dirw ? (TT-8-8*gw) : 8*gw;
        *(uint4*)(ob + t0*2) = od[w];      // 4 stores: one fully-dirty 64B block
      }
    }
  };

  // 16 groups total; ping-pong A/B, prefetch 2 groups ahead after consumption.
  #pragma unroll 1
  for (int gg=0; gg<8; ++gg){
    const int gA = 2*gg, gB = 2*gg+1;
    doGroup(bufA, gA);
    if (gA+2 < 16) ldgrp(bufA, gA+2);
    doGroup(bufB, gB);
    if (gB+2 < 16) ldgrp(bufB, gB+2);
  }

  if (LAST) tail[b*16 + i] = h;
  else      tail[b*16 + dirw*8 + i] = dirw ? tail_bwd : h;
}

// ---------------- fc: layer3-bwd@T-1 (= tanh(proj(tail2))) + FC -------------
__global__ __launch_bounds__(256) void fc_k(
    const float* __restrict__ tail2, const float* __restrict__ tail3,
    const float* __restrict__ Wih3, const float* __restrict__ bih3,
    const float* __restrict__ bhh3,
    const float* __restrict__ fcw, const float* __restrict__ fcb,
    float* __restrict__ outp)
{
  const int b = blockIdx.x*256 + threadIdx.x;
  float inv[16];
  #pragma unroll
  for (int c=0;c<16;c++) inv[c] = tail2[b*16+c];
  float lv[16];
  #pragma unroll
  for (int k=0;k<8;k++) lv[k] = tail3[b*16+k];
  #pragma unroll
  for (int ii=0; ii<8; ++ii){
    float a = bih3[8+ii] + bhh3[8+ii];       // dir=1 rows
    #pragma unroll
    for (int j=0;j<16;j++) a = fmaf(Wih3[(8+ii)*16 + j], inv[j], a);
    lv[8+ii] = fast_tanh(a);
  }
  #pragma unroll
  for (int c=0;c<2;c++){
    float o = fcb[c];
    #pragma unroll
    for (int k=0;k<16;k++) o = fmaf(fcw[c*16+k], lv[k], o);
    outp[b*2+c] = o;
  }
}

extern "C" void kernel_launch(void* const* d_in, const int* in_sizes, int n_in,
                              void* d_out, int out_size, void* d_ws, size_t ws_size,
                              hipStream_t stream)
{
  const float* x    = (const float*)d_in[0];
  const float* Wih0 = (const float*)d_in[1];
  const float* Whh0 = (const float*)d_in[2];
  const float* bih0 = (const float*)d_in[3];
  const float* bhh0 = (const float*)d_in[4];
  const float* Wih  = (const float*)d_in[5];   // [3][2][8][16]
  const float* WhhL = (const float*)d_in[6];   // [3][2][8][8]
  const float* bih  = (const float*)d_in[7];   // [3][2][8]
  const float* bhh  = (const float*)d_in[8];
  const float* fcw  = (const float*)d_in[9];
  const float* fcb  = (const float*)d_in[10];

  const size_t PLANE_E = (size_t)2*BB*8*TT;    // 33.5M elems = 64 MB bf16
  __hip_bfloat16* A  = (__hip_bfloat16*)d_ws;
  __hip_bfloat16* Bb = A + PLANE_E;
  float* tail2 = (float*)(Bb + PLANE_E);       // [B][16] f32
  float* tail3 = tail2 + (size_t)BB*16;
  if (ws_size < PLANE_E*2*sizeof(__hip_bfloat16) + (size_t)BB*16*4*2) return;

  // layer 0
  proj0<<<2048,256,0,stream>>>(x, Wih0, bih0, bhh0, A);
  scanK<0><<<256,256,0,stream>>>(A, Whh0, Bb, tail2);
  // layer 1
  projN<16><<<2048,256,0,stream>>>(Bb, Wih,     bih,    bhh,    A);
  scanK<0><<<256,256,0,stream>>>(A, WhhL,      Bb, tail2);
  // layer 2
  projN<16><<<2048,256,0,stream>>>(Bb, Wih+256, bih+16, bhh+16, A);
  scanK<0><<<256,256,0,stream>>>(A, WhhL+128,  Bb, tail2);
  // layer 3 (fwd only)
  projN<8><<<2048,256,0,stream>>>(Bb, Wih+512, bih+32, bhh+32, A);
  scanK<1><<<128,256,0,stream>>>(A, WhhL+256,  Bb /*unused*/, tail3);
  // layer-3 bwd single step + FC
  fc_k<<<16,256,0,stream>>>(tail2, tail3, Wih+512, bih+32, bhh+32,
                            fcw, fcb, (float*)d_out);
}